// Round 7
// baseline (347.790 us; speedup 1.0000x reference)
//
#include <hip/hip_runtime.h>

typedef unsigned short u16;
typedef short s16x8 __attribute__((ext_vector_type(8)));   // 8 bf16 as raw bits (4 VGPRs)
typedef float f32x4 __attribute__((ext_vector_type(4)));

#define DEV __device__ __forceinline__

#if __has_builtin(__builtin_amdgcn_exp2f)
#define EXP2F(x) __builtin_amdgcn_exp2f(x)
#else
#define EXP2F(x) exp2f(x)
#endif

DEV u16 f2bf(float f) {
  unsigned int u = __float_as_uint(f);
  u = (u + 0x7fffu + ((u >> 16) & 1u)) >> 16;   // RNE
  return (u16)u;
}
DEV float bf2f(u16 h) { return __uint_as_float(((unsigned int)h) << 16); }
// pack hi16(a)|hi16(b)<<16 — bf16 truncation, 1 instr (v_perm_b32)
DEV unsigned int pk_trunc(float lo, float hi) {
  return __builtin_amdgcn_perm(__float_as_uint(hi), __float_as_uint(lo), 0x07060302u);
}

// async global->LDS, 16B per lane; LDS dest is wave-uniform base (HW adds lane*16)
DEV void g2l16(const void* g, void* l) {
  __builtin_amdgcn_global_load_lds(
      (const __attribute__((address_space(1))) unsigned int*)g,
      (__attribute__((address_space(3))) unsigned int*)l, 16, 0, 0);
}

#define SPLANE 6291456        // one z's Q (or K, or V) plane: 8*12*1024*64

#define BAR __builtin_amdgcn_s_barrier()
#define WAIT_VM(n) asm volatile("s_waitcnt vmcnt(" #n ")" ::: "memory")
#define WAIT_LGKM0 asm volatile("s_waitcnt lgkmcnt(0)" ::: "memory")
#define PRIO1 __builtin_amdgcn_s_setprio(1)
#define PRIO0 __builtin_amdgcn_s_setprio(0)

// ---------------- fused fp32 -> bf16 convert (all 5 tensors, one launch) ----------------
__global__ __launch_bounds__(256) void k_cvt(const float* __restrict__ x,
                                             const float* __restrict__ wqi,
                                             const float* __restrict__ wqc,
                                             const float* __restrict__ wpi,
                                             const float* __restrict__ wpc,
                                             u16* __restrict__ xb,
                                             u16* __restrict__ wqkv,
                                             u16* __restrict__ wproj) {
  int i = blockIdx.x * 256 + threadIdx.x;     // float4 index, total 2752512
  const float* src; u16* dst; int off;
  if (i < 1572864)      { src = x;   dst = xb;             off = 0; }
  else if (i < 2015232) { src = wqi; dst = wqkv;           off = 1572864; }
  else if (i < 2457600) { src = wqc; dst = wqkv + 1769472; off = 2015232; }
  else if (i < 2605056) { src = wpi; dst = wproj;          off = 2457600; }
  else                  { src = wpc; dst = wproj + 589824; off = 2605056; }
  int j = i - off;
  float4 v = ((const float4*)src)[j];
  ushort4 o;
  o.x = f2bf(v.x); o.y = f2bf(v.y); o.z = f2bf(v.z); o.w = f2bf(v.w);
  ((ushort4*)dst)[j] = o;
}

// ======================= QKV GEMM: 128x128 tile, 4-wave, dbuf counted-vmcnt =============
// [8192x768] x [2304x768]^T per z. BK=64, 12 K-tiles. 64 KiB LDS double-buffer ->
// 2 blocks/CU, grid 2304 = exactly 9/CU, counted-vmcnt: stage kt+2 after the read-retire
// barrier, WAIT_VM(8) drains only kt+1. First 32 blocks zero sal[]. V-epilogue uses a
// transposed [d][t] strip (stride 88). Control — unchanged from round 6.

DEV void qstg(const u16* pX, const u16* pW, int koff, u16* lA, u16* lB, int wave) {
#pragma unroll
  for (int it = 0; it < 4; ++it) {
    int rb = wave * 32 + it * 8;
    g2l16(pX + koff + it * (8 * 768), &lA[rb * 64]);
    g2l16(pW + koff + it * (8 * 768), &lB[rb * 64]);
  }
}

DEV void qcomp(const u16* lA, const u16* lB, int wr, int wc, int fr, int fq,
               f32x4 (&acc)[4][4]) {
#pragma unroll
  for (int ks = 0; ks < 2; ++ks) {
    s16x8 af[4], bfr[4];
#pragma unroll
    for (int i = 0; i < 4; i++) {
      int row = wc + i * 16 + fr;
      af[i] = *(const s16x8*)&lB[row * 64 + (((ks * 4 + fq) ^ (row & 7)) * 8)];
    }
#pragma unroll
    for (int j = 0; j < 4; j++) {
      int row = wr + j * 16 + fr;
      bfr[j] = *(const s16x8*)&lA[row * 64 + (((ks * 4 + fq) ^ (row & 7)) * 8)];
    }
    PRIO1;
#pragma unroll
    for (int i = 0; i < 4; i++)
#pragma unroll
      for (int j = 0; j < 4; j++)
        acc[i][j] = __builtin_amdgcn_mfma_f32_16x16x32_bf16(af[i], bfr[j], acc[i][j], 0, 0, 0);
    PRIO0;
  }
}

__global__ __launch_bounds__(256, 2) void k_qkv_gemm(const u16* __restrict__ X,
                                                     const u16* __restrict__ Wq,
                                                     u16* __restrict__ QK,
                                                     u16* __restrict__ VT,
                                                     float* __restrict__ sal) {
  __shared__ __align__(16) u16 sm[32768];   // 64 KiB: b0{lA,lB} | b1{lA,lB}; epi unions

  const int idx = blockIdx.x;
  const int tid = threadIdx.x;
  if (idx < 32) sal[idx * 256 + tid] = 0.f;   // zero saliency accumulator for k_attn

  // XCD-chunked bijective swizzle: 2304 = 8 XCD x 288. Per XCD: bx fastest (full W
  // panel 3.5 MB resident in 4 MiB L2), 16 consecutive m-panels, one z.
  const int swz = (idx & 7) * 288 + (idx >> 3);
  const int bx = swz % 18;
  const int rem = swz / 18;                  // 0..127
  const int by = rem & 63;
  const int z = rem >> 6;
  const int n0 = bx * 128, m0 = by * 128;

  const int wave = tid >> 6, lane = tid & 63;
  const int wr = (wave >> 1) * 64, wc = (wave & 1) * 64;
  const int fr = lane & 15, fq = lane >> 4;

  // staging lane constants (pre-swizzled source chunk; LDS dest linear per wave)
  const int srow = lane >> 3;
  const int scol = ((lane & 7) ^ srow) * 8;

  // per-thread staging base pointers (row + swizzled chunk folded in)
  const u16* pX = X + (size_t)(m0 + wave * 32 + srow) * 768 + scol;
  const u16* pW = Wq + (size_t)z * (2304 * 768) + (size_t)(n0 + wave * 32 + srow) * 768 + scol;

  u16* const lA0 = sm;
  u16* const lB0 = sm + 8192;
  u16* const lA1 = sm + 16384;
  u16* const lB1 = sm + 24576;

  f32x4 acc[4][4];   // [i: ch-frag][j: tok-frag]; ch = wc+i*16+fq*4+r, tok = wr+j*16+fr
#pragma unroll
  for (int i = 0; i < 4; i++)
#pragma unroll
    for (int j = 0; j < 4; j++) acc[i][j] = (f32x4){0.f, 0.f, 0.f, 0.f};

  // ---- prologue: tile0 -> b0, tile1 -> b1; drain tile0 only ----
  qstg(pX, pW, 0, lA0, lB0, wave);
  qstg(pX, pW, 64, lA1, lB1, wave);
  WAIT_VM(8);          // tile0 landed; tile1's 8 still in flight
  BAR;

  const u16* pX2 = pX + 128;   // tile-2 column base
  const u16* pW2 = pW + 128;

#pragma unroll
  for (int ii = 0; ii < 6; ++ii) {
    // ---- even K-tile (kt = 2*ii): compute b0 ----
    qcomp(lA0, lB0, wr, wc, fr, fq, acc);
    BAR;                               // all waves done reading b0
    if (ii < 5) {
      qstg(pX2, pW2, 0, lA0, lB0, wave);   // stage kt+2 -> b0
      WAIT_VM(8);                      // kt+1's 8 landed; kt+2's 8 in flight
    } else {
      WAIT_VM(0);                      // kt=10: only stage(11) outstanding -> drain all
    }
    BAR;                               // b1 (kt+1) published
    // ---- odd K-tile (kt = 2*ii+1): compute b1 ----
    qcomp(lA1, lB1, wr, wc, fr, fq, acc);
    BAR;                               // all waves done reading b1
    if (ii < 5) {
      qstg(pX2, pW2, 64, lA1, lB1, wave);  // stage kt+3 -> b1
      WAIT_VM(8);                      // kt+2's 8 landed
      pX2 += 128; pW2 += 128;
    }
    BAR;                               // b0 (kt+2) published
  }

  // ---- epilogue: C^T frags -> LDS strip -> vectorized global stores ----
  __syncthreads();                 // all staging drained (WAIT_VM(0) above) + waves joined
  const int c0 = n0 + wc;          // 64-col slab = exactly one head
  const int t0 = m0 + wr;
  const int b = t0 >> 10, tt0 = t0 & 1023;
  if (c0 < 1536) {                 // Q or K: [t][c] strip (stride 72), row-major store
    u16* ep = sm + wave * 4608;    // 64 t-rows x 72 stride (c cols)
#pragma unroll
    for (int i = 0; i < 4; i++)
#pragma unroll
      for (int j = 0; j < 4; j++) {
        unsigned int lo = (unsigned int)f2bf(acc[i][j][0]) | ((unsigned int)f2bf(acc[i][j][1]) << 16);
        unsigned int hi = (unsigned int)f2bf(acc[i][j][2]) | ((unsigned int)f2bf(acc[i][j][3]) << 16);
        uint2 pk; pk.x = lo; pk.y = hi;
        *(uint2*)&ep[(j * 16 + fr) * 72 + i * 16 + fq * 4] = pk;
      }
    __builtin_amdgcn_s_waitcnt(0);   // wave-local LDS RAW (vmcnt already 0 here)
    const int three = (c0 >= 768) ? 1 : 0;
    const int h = (c0 - three * 768) >> 6;
    u16* dst = QK + ((size_t)z * 2 + three) * SPLANE +
               ((size_t)(b * 12 + h) * 1024 + tt0) * 64;
#pragma unroll
    for (int pass = 0; pass < 8; ++pass) {
      int row = pass * 8 + (lane >> 3);
      int dch = (lane & 7) * 8;
      *(uint4*)&dst[(size_t)row * 64 + dch] = *(const uint4*)&ep[row * 72 + dch];
    }
  } else {                         // V: transposed [d][t] strip (stride 88 -> 8-bank spread)
    const int h = (c0 - 1536) >> 6;
    u16* dst = VT + (size_t)z * SPLANE + ((size_t)(b * 12 + h) * 64) * 1024 + tt0;
    u16* ep2 = sm + wave * 5632;   // 64 d-rows x 88 stride (t cols)
#pragma unroll
    for (int i = 0; i < 4; i++)
#pragma unroll
      for (int j = 0; j < 4; j++)
#pragma unroll
        for (int r = 0; r < 4; r++)
          ep2[(i * 16 + fq * 4 + r) * 88 + j * 16 + fr] = f2bf(acc[i][j][r]);
    __builtin_amdgcn_s_waitcnt(0);   // wave-local LDS RAW
#pragma unroll
    for (int pass = 0; pass < 8; ++pass) {
      int d = pass * 8 + (lane >> 3);
      int tch = (lane & 7) * 8;
      *(uint4*)&dst[(size_t)d * 1024 + tch] = *(const uint4*)&ep2[d * 88 + tch];
    }
  }
}

// ---------------- flash attention: 256 Q/block (64/wave), 64 KV/iter ----------------
// XCD-grouped block swizzle (grid 768 = 8 XCD x 96; all 4 q-blocks of a (z,bh) pair
// co-XCD -> K/V L2-resident, r6: FETCH 116.8->44.6 MB). Fused Gram-Schmidt prologue.
// ROUND-7: K/V staging converted from reg round-trip (syncthreads -> 16 LDS publishes
// -> syncthreads on every wave's critical path, VALU-heavy) to async global_load_lds
// double-buffer with counted vmcnt (qkv's proven pattern): stage tile t+2 into the
// just-retired buffer after the read-retire barrier, WAIT_VM(4) drains only t+1 -> 
// loads stay in flight across barriers. K/V LDS rows are 64 u16 with XOR-swizzled 16B
// chunks (pre-swizzled global source, qkv's scheme); frag reads use the same swizzle.
// setprio around MFMA clusters (T5: +4-7% on attn, m191). LDS 53,248 B -> 3 blocks/CU.
#define PST 40   // lP row stride (80 B, 16B-aligned)
__global__ __launch_bounds__(256, 3) void k_attn(const u16* __restrict__ QK,
                                                 const u16* __restrict__ VT,
                                                 const float* __restrict__ orth_scale,
                                                 float* __restrict__ sal,
                                                 u16* __restrict__ aout) {
  __shared__ __align__(16) u16 sm[26624];  // lK0 4096 | lV0 | lK1 | lV1 | lP 4x2560
  const int lid = blockIdx.x;               // 0..767
  const int swz = (lid & 7) * 96 + (lid >> 3);
  const int qb = swz & 3;
  const int pr = swz >> 2;                  // 0..191 (z,bh) pair
  const int z = pr / 96, bh = pr - (pr / 96) * 96;
  const int q0 = qb * 256;
  const int b = bh / 12, hd = bh - b * 12;
  const size_t plane = (size_t)bh * 65536;
  const u16* Q  = QK + (size_t)z * 2 * SPLANE + plane;
  const u16* K  = QK + ((size_t)z * 2 + 1) * SPLANE + plane;
  const u16* Vt = VT + (size_t)z * SPLANE + plane;   // [64 d][1024 n]

  const int tid = threadIdx.x, wave = tid >> 6, lane = tid & 63;
  const int fr = lane & 15, fq = lane >> 4;
  u16* lP = sm + 16384 + wave * 2560;  // 64 m-rows x PST (n-half cols)

  s16x8 qf[4][2];
#pragma unroll
  for (int s = 0; s < 4; s++) {
    const u16* qrow = Q + (size_t)(q0 + wave * 64 + s * 16 + fr) * 64;
    qf[s][0] = *(const s16x8*)&qrow[fq * 8];
    qf[s][1] = *(const s16x8*)&qrow[32 + fq * 8];
  }

  if (z == 0) {   // fused Gram-Schmidt ortho + saliency (q_id rows, this head)
    const float scale = fminf(fmaxf(orth_scale[0], 0.f), 1.f);
    const u16* Qc = QK + (size_t)2 * SPLANE + plane;   // z=1 Q plane, same (b,h)
#pragma unroll
    for (int s = 0; s < 4; s++) {
      const u16* qcrow = Qc + (size_t)(q0 + wave * 64 + s * 16 + fr) * 64;
      s16x8 qc0 = *(const s16x8*)&qcrow[fq * 8];
      s16x8 qc1 = *(const s16x8*)&qcrow[32 + fq * 8];
      float d = 0.f, nq = 0.f;
#pragma unroll
      for (int e = 0; e < 8; e++) {
        float a0 = bf2f((u16)qf[s][0][e]), a1 = bf2f((u16)qf[s][1][e]);
        float c0 = bf2f((u16)qc0[e]),      c1 = bf2f((u16)qc1[e]);
        d  = fmaf(a0, c0, fmaf(a1, c1, d));
        nq = fmaf(c0, c0, fmaf(c1, c1, nq));
      }
      d += __shfl_xor(d, 16);  d += __shfl_xor(d, 32);
      nq += __shfl_xor(nq, 16); nq += __shfl_xor(nq, 32);
      nq += 1e-5f;
      float coeff = fminf(fmaxf(d / nq, -1.f), 1.f);
      float sc = scale * coeff;
#pragma unroll
      for (int e = 0; e < 8; e++) {
        qf[s][0][e] = (short)f2bf(bf2f((u16)qf[s][0][e]) - sc * bf2f((u16)qc0[e]));
        qf[s][1][e] = (short)f2bf(bf2f((u16)qf[s][1][e]) - sc * bf2f((u16)qc1[e]));
      }
      if (lane < 16)
        atomicAdd(&sal[b * 1024 + q0 + wave * 64 + s * 16 + fr], fabsf(d) / sqrtf(nq));
    }
  }

  f32x4 oacc[4][4];            // [s][jt: d-tile], value (m = fq*4+r, d = jt*16+fr)
  float lsum[4];
#pragma unroll
  for (int s = 0; s < 4; s++) {
    lsum[s] = 0.f;
#pragma unroll
    for (int j = 0; j < 4; j++) oacc[s][j] = (f32x4){0.f, 0.f, 0.f, 0.f};
  }

  // staging lane constants (pre-swizzled source chunk; LDS dest linear per wave)
  const int r8 = lane >> 3;
  const int csrc = ((lane & 7) ^ r8) * 8;
  // per-thread global staging bases: wave w stages rows [w*8, w*8+8) and +32 of each tile
  const u16* pK = K + (size_t)(wave * 8 + r8) * 64 + csrc;     // +t*4096 per tile
  const u16* pV = Vt + (size_t)(wave * 8 + r8) * 1024 + csrc;  // +t*64 per tile

  // prologue: tile0 -> buf0, tile1 -> buf1; drain tile0's 4 only
  {
    u16* bK = sm;            u16* bV = sm + 4096;
    g2l16(pK,          bK + wave * 512);
    g2l16(pK + 2048,   bK + 2048 + wave * 512);
    g2l16(pV,          bV + wave * 512);
    g2l16(pV + 32768,  bV + 2048 + wave * 512);
    bK = sm + 8192;          bV = sm + 12288;
    g2l16(pK + 4096,         bK + wave * 512);
    g2l16(pK + 4096 + 2048,  bK + 2048 + wave * 512);
    g2l16(pV + 64,           bV + wave * 512);
    g2l16(pV + 64 + 32768,   bV + 2048 + wave * 512);
  }
  WAIT_VM(4);
  BAR;

  for (int t = 0; t < 16; ++t) {
    const int cb = (t & 1) * 8192;
    const u16* lK  = sm + cb;
    const u16* lVT = sm + cb + 4096;

#pragma unroll
    for (int ph = 0; ph < 2; ++ph) {           // n-half: n in [ph*32, ph*32+32)
#pragma unroll
      for (int jh = 0; jh < 2; ++jh) {
        const int jt = ph * 2 + jh;
        const int krow = (jt * 16 + fr) * 64;
        s16x8 kf0 = *(const s16x8*)&lK[krow + ((fq ^ (fr & 7)) * 8)];
        s16x8 kf1 = *(const s16x8*)&lK[krow + (((fq + 4) ^ (fr & 7)) * 8)];
        PRIO1;
#pragma unroll
        for (int s = 0; s < 4; s++) {
          f32x4 t2 = (f32x4){0.f, 0.f, 0.f, 0.f};
          t2 = __builtin_amdgcn_mfma_f32_16x16x32_bf16(kf0, qf[s][0], t2, 0, 0, 0);
          t2 = __builtin_amdgcn_mfma_f32_16x16x32_bf16(kf1, qf[s][1], t2, 0, 0, 0);
          float p0 = EXP2F(fmaf(t2[0], 0.18033688f, -28.8539008f));
          float p1 = EXP2F(fmaf(t2[1], 0.18033688f, -28.8539008f));
          float p2 = EXP2F(fmaf(t2[2], 0.18033688f, -28.8539008f));
          float p3 = EXP2F(fmaf(t2[3], 0.18033688f, -28.8539008f));
          lsum[s] += (p0 + p1) + (p2 + p3);
          uint2 pk; pk.x = pk_trunc(p0, p1); pk.y = pk_trunc(p2, p3);
          *(uint2*)&lP[(s * 16 + fr) * PST + jh * 16 + fq * 4] = pk;   // rows m, cols n-half
        }
        PRIO0;
      }
      WAIT_LGKM0;                     // wave-local LDS RAW on lP (vmcnt stays in flight)
      s16x8 pa[4];
#pragma unroll
      for (int s = 0; s < 4; s++) pa[s] = *(const s16x8*)&lP[(s * 16 + fr) * PST + fq * 8];
      PRIO1;
#pragma unroll
      for (int jt = 0; jt < 4; jt++) {
        s16x8 vb = *(const s16x8*)&lVT[(jt * 16 + fr) * 64 + (((ph * 4 + fq) ^ (fr & 7)) * 8)];
#pragma unroll
        for (int s = 0; s < 4; s++)
          oacc[s][jt] = __builtin_amdgcn_mfma_f32_16x16x32_bf16(pa[s], vb, oacc[s][jt], 0, 0, 0);
      }
      PRIO0;
    }

    BAR;                               // all waves done reading buf[t&1]
    if (t < 14) {
      u16* bK = sm + cb;  u16* bV = sm + cb + 4096;
      const u16* nK = pK + (size_t)(t + 2) * 4096;
      const u16* nV = pV + (size_t)(t + 2) * 64;
      g2l16(nK,          bK + wave * 512);
      g2l16(nK + 2048,   bK + 2048 + wave * 512);
      g2l16(nV,          bV + wave * 512);
      g2l16(nV + 32768,  bV + 2048 + wave * 512);
      WAIT_VM(4);                      // tile t+1's 4 landed; t+2's 4 in flight
    } else if (t == 14) {
      WAIT_VM(0);                      // only tile 15's 4 outstanding -> drain
    }
    BAR;                               // buf[(t+1)&1] published
  }

  // lsum: reduce across the 4 fq-groups of each m-column, then distribute
#pragma unroll
  for (int s = 0; s < 4; s++) {
    float v = lsum[s];
    v += __shfl_xor(v, 16);
    v += __shfl_xor(v, 32);
    lsum[s] = v;                  // lanes 0..15 now hold totals for m = fr
  }
#pragma unroll
  for (int s = 0; s < 4; s++) {
#pragma unroll
    for (int r = 0; r < 4; r++) {
      float inv = 1.f / __shfl(lsum[s], fq * 4 + r);
      int t = q0 + wave * 64 + s * 16 + fq * 4 + r;
      size_t base = ((size_t)z * 8192 + b * 1024 + t) * 768 + hd * 64 + fr;
#pragma unroll
      for (int jt = 0; jt < 4; jt++)
        aout[base + jt * 16] = f2bf(oacc[s][jt][r] * inv);
    }
  }
}

// ---------------- proj GEMM + bias -> bf16 (BK=64, swizzled, C^T, LDS epilogue) ---------
// XCD-grouped swizzle: grid 768 = 8 XCD x 96. First 32 blocks also finalize saliency
// (sal = clip(sal/12)) — attn completed before proj launches (stream order).
__global__ __launch_bounds__(256) void k_proj_gemm(const u16* __restrict__ A,
                                                   const u16* __restrict__ Wp,
                                                   const float* __restrict__ bias_id,
                                                   const float* __restrict__ bias_cl,
                                                   float* __restrict__ sal,
                                                   u16* __restrict__ out) {
  __shared__ __align__(16) u16 sm[18432];   // lA 8192 | lB 8192 / epilogue union
  u16* lA = sm;
  u16* lB = sm + 8192;
  const int idx = blockIdx.x;               // 0..767
  const int tid = threadIdx.x;
  if (idx < 32) {
    int i2 = idx * 256 + tid;               // 8192 saliency rows
    float v = sal[i2] * (1.f / 12.f);
    sal[i2] = fminf(fmaxf(v, 0.f), 1.f);
  }
  const int swz = (idx & 7) * 96 + (idx >> 3);
  const int bx = swz % 6;
  const int rem = swz / 6;                  // 0..127
  const int by = rem & 63;
  const int z = rem >> 6;
  const int n0 = bx * 128, m0 = by * 128;
  const u16* Az = A + (size_t)z * 8192 * 768;
  const u16* Wz = Wp + (size_t)z * 768 * 768;
  const float* bias = z ? bias_cl : bias_id;
  u16* oz = out + (size_t)z * 8192 * 768;
  const int wave = tid >> 6, lane = tid & 63;
  const int wr = (wave >> 1) * 64, wc = (wave & 1) * 64;
  const int fr = lane & 15, fq = lane >> 4;

  float bv[4][4];
#pragma unroll
  for (int i = 0; i < 4; i++)
#pragma unroll
    for (int r = 0; r < 4; r++) bv[i][r] = bias[n0 + wc + i * 16 + fq * 4 + r];

  f32x4 acc[4][4];
#pragma unroll
  for (int i = 0; i < 4; i++)
#pragma unroll
    for (int j = 0; j < 4; j++) acc[i][j] = (f32x4){0.f, 0.f, 0.f, 0.f};

  const int srow = lane >> 3;
  const int scol = ((lane & 7) ^ srow) * 8;

  // per-thread staging base pointers (row + swizzled chunk folded in)
  const u16* pAz = Az + (size_t)(m0 + wave * 32 + srow) * 768 + scol;
  const u16* pWz = Wz + (size_t)(n0 + wave * 32 + srow) * 768 + scol;

  for (int k0 = 0; k0 < 768; k0 += 64) {
    __syncthreads();
#pragma unroll
    for (int it = 0; it < 4; ++it) {
      int rb = wave * 32 + it * 8;
      g2l16(pAz + it * (8 * 768) + k0, &lA[rb * 64]);
      g2l16(pWz + it * (8 * 768) + k0, &lB[rb * 64]);
    }
    __syncthreads();
#pragma unroll
    for (int ks = 0; ks < 2; ++ks) {
      s16x8 af[4], bfr[4];
#pragma unroll
      for (int i = 0; i < 4; i++) {
        int row = wc + i * 16 + fr;
        af[i] = *(const s16x8*)&lB[row * 64 + (((ks * 4 + fq) ^ (row & 7)) * 8)];
      }
#pragma unroll
      for (int j = 0; j < 4; j++) {
        int row = wr + j * 16 + fr;
        bfr[j] = *(const s16x8*)&lA[row * 64 + (((ks * 4 + fq) ^ (row & 7)) * 8)];
      }
#pragma unroll
      for (int i = 0; i < 4; i++)
#pragma unroll
        for (int j = 0; j < 4; j++)
          acc[i][j] = __builtin_amdgcn_mfma_f32_16x16x32_bf16(af[i], bfr[j], acc[i][j], 0, 0, 0);
    }
  }

  __syncthreads();
  u16* ep = sm + wave * 4608;      // 64 t-rows x 72 stride (c cols)
#pragma unroll
  for (int i = 0; i < 4; i++)
#pragma unroll
    for (int j = 0; j < 4; j++) {
      unsigned int lo = (unsigned int)f2bf(acc[i][j][0] + bv[i][0]) |
                        ((unsigned int)f2bf(acc[i][j][1] + bv[i][1]) << 16);
      unsigned int hi = (unsigned int)f2bf(acc[i][j][2] + bv[i][2]) |
                        ((unsigned int)f2bf(acc[i][j][3] + bv[i][3]) << 16);
      uint2 pk; pk.x = lo; pk.y = hi;
      *(uint2*)&ep[(j * 16 + fr) * 72 + i * 16 + fq * 4] = pk;
    }
  __builtin_amdgcn_s_waitcnt(0);

  const int c0 = n0 + wc;
#pragma unroll
  for (int pass = 0; pass < 8; ++pass) {
    int row = pass * 8 + (lane >> 3);
    int dch = (lane & 7) * 8;
    u16* dst = oz + (size_t)(m0 + wr + row) * 768 + c0;
    *(uint4*)&dst[dch] = *(const uint4*)&ep[row * 72 + dch];
  }
}

// ---------------- LayerNorm (bf16 in, fp32 out) ----------------
__global__ __launch_bounds__(256) void k_ln(const u16* __restrict__ pin,
                                            const float* __restrict__ w_id,
                                            const float* __restrict__ b_id,
                                            const float* __restrict__ w_cl,
                                            const float* __restrict__ b_cl,
                                            float* __restrict__ out) {
  __shared__ float red[2][8];
  const int row = blockIdx.x;     // 0..16383
  const int z = row >> 13;
  const float* w = z ? w_cl : w_id;
  const float* bb = z ? b_cl : b_id;
  const u16* x = pin + (size_t)row * 768;
  float v[3];
  float s = 0.f, s2 = 0.f;
#pragma unroll
  for (int i = 0; i < 3; i++) {
    v[i] = bf2f(x[threadIdx.x + i * 256]);
    s += v[i];
    s2 += v[i] * v[i];
  }
#pragma unroll
  for (int sh = 1; sh < 64; sh <<= 1) { s += __shfl_xor(s, sh); s2 += __shfl_xor(s2, sh); }
  const int wave = threadIdx.x >> 6, lane = threadIdx.x & 63;
  if (lane == 0) { red[0][wave] = s; red[1][wave] = s2; }
  __syncthreads();
  s = red[0][0] + red[0][1] + red[0][2] + red[0][3];
  s2 = red[1][0] + red[1][1] + red[1][2] + red[1][3];
  float mu = s * (1.f / 768.f);
  float var = s2 * (1.f / 768.f) - mu * mu;
  float rstd = rsqrtf(fmaxf(var, 0.f) + 1e-5f);
  float* o = out + (size_t)row * 768;
#pragma unroll
  for (int i = 0; i < 3; i++) {
    int c = threadIdx.x + i * 256;
    o[c] = (v[i] - mu) * rstd * w[c] + bb[c];
  }
}

extern "C" void kernel_launch(void* const* d_in, const int* in_sizes, int n_in,
                              void* d_out, int out_size, void* d_ws, size_t ws_size,
                              hipStream_t stream) {
  const float* x        = (const float*)d_in[0];
  const float* w_qkv_id = (const float*)d_in[1];
  const float* w_qkv_cl = (const float*)d_in[2];
  const float* w_proj_id= (const float*)d_in[3];
  const float* b_proj_id= (const float*)d_in[4];
  const float* w_proj_cl= (const float*)d_in[5];
  const float* b_proj_cl= (const float*)d_in[6];
  const float* ln_id_w  = (const float*)d_in[7];
  const float* ln_id_b  = (const float*)d_in[8];
  const float* ln_cl_w  = (const float*)d_in[9];
  const float* ln_cl_b  = (const float*)d_in[10];
  const float* orth     = (const float*)d_in[11];
  float* out = (float*)d_out;
  float* sal = out + 12582912;

  // workspace layout (122.68 MB total)
  u16* xb    = (u16*)d_ws;                   //  6,291,456 u16
  u16* wqkv  = xb + 6291456;                 //  3,538,944 u16 (id then cloth)
  u16* wproj = wqkv + 3538944;               //  1,179,648 u16 (id then cloth)
  u16* qk    = wproj + 1179648;              // 25,165,824 u16 [2][{q,k}][b][h][n][d]
  u16* vt    = qk + 25165824;                // 12,582,912 u16 [2][b][h][d][n]
  u16* aout  = vt + 12582912;                // 12,582,912 u16 [2][B*N][C]
  u16* pout  = qk;                           // bf16 proj out aliases dead qk

  k_cvt<<<10752, 256, 0, stream>>>(x, w_qkv_id, w_qkv_cl, w_proj_id, w_proj_cl,
                                   xb, wqkv, wproj);
  k_qkv_gemm<<<2304, 256, 0, stream>>>(xb, wqkv, qk, vt, sal);
  k_attn<<<768, 256, 0, stream>>>(qk, vt, orth, sal, aout);
  k_proj_gemm<<<768, 256, 0, stream>>>(aout, wproj, b_proj_id, b_proj_cl, sal, pout);
  k_ln<<<16384, 256, 0, stream>>>(pout, ln_id_w, ln_id_b, ln_cl_w, ln_cl_b, out);
}

// Round 8
// 275.203 us; speedup vs baseline: 1.2638x; 1.2638x over previous
//
#include <hip/hip_runtime.h>

typedef unsigned short u16;
typedef short s16x8 __attribute__((ext_vector_type(8)));   // 8 bf16 as raw bits (4 VGPRs)
typedef float f32x4 __attribute__((ext_vector_type(4)));

#define DEV __device__ __forceinline__

#if __has_builtin(__builtin_amdgcn_exp2f)
#define EXP2F(x) __builtin_amdgcn_exp2f(x)
#else
#define EXP2F(x) exp2f(x)
#endif

DEV u16 f2bf(float f) {
  unsigned int u = __float_as_uint(f);
  u = (u + 0x7fffu + ((u >> 16) & 1u)) >> 16;   // RNE
  return (u16)u;
}
DEV float bf2f(u16 h) { return __uint_as_float(((unsigned int)h) << 16); }
// pack hi16(a)|hi16(b)<<16 — bf16 truncation, 1 instr (v_perm_b32)
DEV unsigned int pk_trunc(float lo, float hi) {
  return __builtin_amdgcn_perm(__float_as_uint(hi), __float_as_uint(lo), 0x07060302u);
}

// async global->LDS, 16B per lane; LDS dest is wave-uniform base (HW adds lane*16)
DEV void g2l16(const void* g, void* l) {
  __builtin_amdgcn_global_load_lds(
      (const __attribute__((address_space(1))) unsigned int*)g,
      (__attribute__((address_space(3))) unsigned int*)l, 16, 0, 0);
}

#define SPLANE 6291456        // one z's Q (or K, or V) plane: 8*12*1024*64

#define BAR __builtin_amdgcn_s_barrier()
#define WAIT_VM(n) asm volatile("s_waitcnt vmcnt(" #n ")" ::: "memory")
#define WAIT_LGKM0 asm volatile("s_waitcnt lgkmcnt(0)" ::: "memory")
#define PRIO1 __builtin_amdgcn_s_setprio(1)
#define PRIO0 __builtin_amdgcn_s_setprio(0)

// ---------------- fused fp32 -> bf16 convert (all 5 tensors, one launch) ----------------
__global__ __launch_bounds__(256) void k_cvt(const float* __restrict__ x,
                                             const float* __restrict__ wqi,
                                             const float* __restrict__ wqc,
                                             const float* __restrict__ wpi,
                                             const float* __restrict__ wpc,
                                             u16* __restrict__ xb,
                                             u16* __restrict__ wqkv,
                                             u16* __restrict__ wproj) {
  int i = blockIdx.x * 256 + threadIdx.x;     // float4 index, total 2752512
  const float* src; u16* dst; int off;
  if (i < 1572864)      { src = x;   dst = xb;             off = 0; }
  else if (i < 2015232) { src = wqi; dst = wqkv;           off = 1572864; }
  else if (i < 2457600) { src = wqc; dst = wqkv + 1769472; off = 2015232; }
  else if (i < 2605056) { src = wpi; dst = wproj;          off = 2457600; }
  else                  { src = wpc; dst = wproj + 589824; off = 2605056; }
  int j = i - off;
  float4 v = ((const float4*)src)[j];
  ushort4 o;
  o.x = f2bf(v.x); o.y = f2bf(v.y); o.z = f2bf(v.z); o.w = f2bf(v.w);
  ((ushort4*)dst)[j] = o;
}

// ======================= QKV GEMM: 128x128 tile, 4-wave, dbuf counted-vmcnt =============
// [8192x768] x [2304x768]^T per z. BK=64, 12 K-tiles. 64 KiB LDS double-buffer ->
// 2 blocks/CU, grid 2304 = exactly 9/CU, counted-vmcnt: stage kt+2 after the read-retire
// barrier, WAIT_VM(8) drains only kt+1. First 32 blocks zero sal[]. V-epilogue uses a
// transposed [d][t] strip (stride 88). Control — unchanged since round 6.

DEV void qstg(const u16* pX, const u16* pW, int koff, u16* lA, u16* lB, int wave) {
#pragma unroll
  for (int it = 0; it < 4; ++it) {
    int rb = wave * 32 + it * 8;
    g2l16(pX + koff + it * (8 * 768), &lA[rb * 64]);
    g2l16(pW + koff + it * (8 * 768), &lB[rb * 64]);
  }
}

DEV void qcomp(const u16* lA, const u16* lB, int wr, int wc, int fr, int fq,
               f32x4 (&acc)[4][4]) {
#pragma unroll
  for (int ks = 0; ks < 2; ++ks) {
    s16x8 af[4], bfr[4];
#pragma unroll
    for (int i = 0; i < 4; i++) {
      int row = wc + i * 16 + fr;
      af[i] = *(const s16x8*)&lB[row * 64 + (((ks * 4 + fq) ^ (row & 7)) * 8)];
    }
#pragma unroll
    for (int j = 0; j < 4; j++) {
      int row = wr + j * 16 + fr;
      bfr[j] = *(const s16x8*)&lA[row * 64 + (((ks * 4 + fq) ^ (row & 7)) * 8)];
    }
    PRIO1;
#pragma unroll
    for (int i = 0; i < 4; i++)
#pragma unroll
      for (int j = 0; j < 4; j++)
        acc[i][j] = __builtin_amdgcn_mfma_f32_16x16x32_bf16(af[i], bfr[j], acc[i][j], 0, 0, 0);
    PRIO0;
  }
}

__global__ __launch_bounds__(256, 2) void k_qkv_gemm(const u16* __restrict__ X,
                                                     const u16* __restrict__ Wq,
                                                     u16* __restrict__ QK,
                                                     u16* __restrict__ VT,
                                                     float* __restrict__ sal) {
  __shared__ __align__(16) u16 sm[32768];   // 64 KiB: b0{lA,lB} | b1{lA,lB}; epi unions

  const int idx = blockIdx.x;
  const int tid = threadIdx.x;
  if (idx < 32) sal[idx * 256 + tid] = 0.f;   // zero saliency accumulator for k_attn

  // XCD-chunked bijective swizzle: 2304 = 8 XCD x 288. Per XCD: bx fastest (full W
  // panel 3.5 MB resident in 4 MiB L2), 16 consecutive m-panels, one z.
  const int swz = (idx & 7) * 288 + (idx >> 3);
  const int bx = swz % 18;
  const int rem = swz / 18;                  // 0..127
  const int by = rem & 63;
  const int z = rem >> 6;
  const int n0 = bx * 128, m0 = by * 128;

  const int wave = tid >> 6, lane = tid & 63;
  const int wr = (wave >> 1) * 64, wc = (wave & 1) * 64;
  const int fr = lane & 15, fq = lane >> 4;

  // staging lane constants (pre-swizzled source chunk; LDS dest linear per wave)
  const int srow = lane >> 3;
  const int scol = ((lane & 7) ^ srow) * 8;

  // per-thread staging base pointers (row + swizzled chunk folded in)
  const u16* pX = X + (size_t)(m0 + wave * 32 + srow) * 768 + scol;
  const u16* pW = Wq + (size_t)z * (2304 * 768) + (size_t)(n0 + wave * 32 + srow) * 768 + scol;

  u16* const lA0 = sm;
  u16* const lB0 = sm + 8192;
  u16* const lA1 = sm + 16384;
  u16* const lB1 = sm + 24576;

  f32x4 acc[4][4];   // [i: ch-frag][j: tok-frag]; ch = wc+i*16+fq*4+r, tok = wr+j*16+fr
#pragma unroll
  for (int i = 0; i < 4; i++)
#pragma unroll
    for (int j = 0; j < 4; j++) acc[i][j] = (f32x4){0.f, 0.f, 0.f, 0.f};

  // ---- prologue: tile0 -> b0, tile1 -> b1; drain tile0 only ----
  qstg(pX, pW, 0, lA0, lB0, wave);
  qstg(pX, pW, 64, lA1, lB1, wave);
  WAIT_VM(8);          // tile0 landed; tile1's 8 still in flight
  BAR;

  const u16* pX2 = pX + 128;   // tile-2 column base
  const u16* pW2 = pW + 128;

#pragma unroll
  for (int ii = 0; ii < 6; ++ii) {
    // ---- even K-tile (kt = 2*ii): compute b0 ----
    qcomp(lA0, lB0, wr, wc, fr, fq, acc);
    BAR;                               // all waves done reading b0
    if (ii < 5) {
      qstg(pX2, pW2, 0, lA0, lB0, wave);   // stage kt+2 -> b0
      WAIT_VM(8);                      // kt+1's 8 landed; kt+2's 8 in flight
    } else {
      WAIT_VM(0);                      // kt=10: only stage(11) outstanding -> drain all
    }
    BAR;                               // b1 (kt+1) published
    // ---- odd K-tile (kt = 2*ii+1): compute b1 ----
    qcomp(lA1, lB1, wr, wc, fr, fq, acc);
    BAR;                               // all waves done reading b1
    if (ii < 5) {
      qstg(pX2, pW2, 64, lA1, lB1, wave);  // stage kt+3 -> b1
      WAIT_VM(8);                      // kt+2's 8 landed
      pX2 += 128; pW2 += 128;
    }
    BAR;                               // b0 (kt+2) published
  }

  // ---- epilogue: C^T frags -> LDS strip -> vectorized global stores ----
  __syncthreads();                 // all staging drained (WAIT_VM(0) above) + waves joined
  const int c0 = n0 + wc;          // 64-col slab = exactly one head
  const int t0 = m0 + wr;
  const int b = t0 >> 10, tt0 = t0 & 1023;
  if (c0 < 1536) {                 // Q or K: [t][c] strip (stride 72), row-major store
    u16* ep = sm + wave * 4608;    // 64 t-rows x 72 stride (c cols)
#pragma unroll
    for (int i = 0; i < 4; i++)
#pragma unroll
      for (int j = 0; j < 4; j++) {
        unsigned int lo = (unsigned int)f2bf(acc[i][j][0]) | ((unsigned int)f2bf(acc[i][j][1]) << 16);
        unsigned int hi = (unsigned int)f2bf(acc[i][j][2]) | ((unsigned int)f2bf(acc[i][j][3]) << 16);
        uint2 pk; pk.x = lo; pk.y = hi;
        *(uint2*)&ep[(j * 16 + fr) * 72 + i * 16 + fq * 4] = pk;
      }
    __builtin_amdgcn_s_waitcnt(0);   // wave-local LDS RAW (vmcnt already 0 here)
    const int three = (c0 >= 768) ? 1 : 0;
    const int h = (c0 - three * 768) >> 6;
    u16* dst = QK + ((size_t)z * 2 + three) * SPLANE +
               ((size_t)(b * 12 + h) * 1024 + tt0) * 64;
#pragma unroll
    for (int pass = 0; pass < 8; ++pass) {
      int row = pass * 8 + (lane >> 3);
      int dch = (lane & 7) * 8;
      *(uint4*)&dst[(size_t)row * 64 + dch] = *(const uint4*)&ep[row * 72 + dch];
    }
  } else {                         // V: transposed [d][t] strip (stride 88 -> 8-bank spread)
    const int h = (c0 - 1536) >> 6;
    u16* dst = VT + (size_t)z * SPLANE + ((size_t)(b * 12 + h) * 64) * 1024 + tt0;
    u16* ep2 = sm + wave * 5632;   // 64 d-rows x 88 stride (t cols)
#pragma unroll
    for (int i = 0; i < 4; i++)
#pragma unroll
      for (int j = 0; j < 4; j++)
#pragma unroll
        for (int r = 0; r < 4; r++)
          ep2[(i * 16 + fq * 4 + r) * 88 + j * 16 + fr] = f2bf(acc[i][j][r]);
    __builtin_amdgcn_s_waitcnt(0);   // wave-local LDS RAW
#pragma unroll
    for (int pass = 0; pass < 8; ++pass) {
      int d = pass * 8 + (lane >> 3);
      int tch = (lane & 7) * 8;
      *(uint4*)&dst[(size_t)d * 1024 + tch] = *(const uint4*)&ep2[d * 88 + tch];
    }
  }
}

// ---------------- flash attention: 256 Q/block (64/wave), 64 KV/iter ----------------
// ROUND-8: REVERT to the round-6 structure (register-prefetch pipeline). Round-7's
// g2l16 async K/V staging regressed 76 -> 132 us: FETCH 44.6 -> 170 MB (4x K/V refetch
// — co-XCD L2 sharing collapsed) + 116 MB of unexplained HBM writes. PITFALL: direct
// global_load_lds K/V streaming in this kernel shape destroys L2 locality; the
// reg-prefetch publish was never the bottleneck.
// Structure: XCD-grouped block swizzle (grid 768 = 8 XCD x 96; all 4 q-blocks of a
// (z,bh) pair co-XCD -> K/V L2-resident). Fused Gram-Schmidt prologue. lgkmcnt-only
// P-exchange wait (prefetch loads stay in flight).
#define AST 72   // lK/lVT row stride (144 B, 16B-aligned)
#define PST 40   // lP row stride (80 B, 16B-aligned)
__global__ __launch_bounds__(256, 3) void k_attn(const u16* __restrict__ QK,
                                                 const u16* __restrict__ VT,
                                                 const float* __restrict__ orth_scale,
                                                 float* __restrict__ sal,
                                                 u16* __restrict__ aout) {
  __shared__ __align__(16) u16 sm[19456];  // lK 64x72 | lVT 64x72 | lP 4 x 64x40
  u16* lK = sm;
  u16* lVT = sm + 4608;
  const int lid = blockIdx.x;               // 0..767
  const int swz = (lid & 7) * 96 + (lid >> 3);
  const int qb = swz & 3;
  const int pr = swz >> 2;                  // 0..191 (z,bh) pair
  const int z = pr / 96, bh = pr - (pr / 96) * 96;
  const int q0 = qb * 256;
  const int b = bh / 12, hd = bh - b * 12;
  const size_t plane = (size_t)bh * 65536;
  const u16* Q  = QK + (size_t)z * 2 * SPLANE + plane;
  const u16* K  = QK + ((size_t)z * 2 + 1) * SPLANE + plane;
  const u16* Vt = VT + (size_t)z * SPLANE + plane;   // [64 d][1024 n]

  const int tid = threadIdx.x, wave = tid >> 6, lane = tid & 63;
  const int fr = lane & 15, fq = lane >> 4;
  u16* lP = sm + 9216 + wave * 2560;   // 64 m-rows x PST (n-half cols)

  s16x8 qf[4][2];
#pragma unroll
  for (int s = 0; s < 4; s++) {
    const u16* qrow = Q + (size_t)(q0 + wave * 64 + s * 16 + fr) * 64;
    qf[s][0] = *(const s16x8*)&qrow[fq * 8];
    qf[s][1] = *(const s16x8*)&qrow[32 + fq * 8];
  }

  if (z == 0) {   // fused Gram-Schmidt ortho + saliency (q_id rows, this head)
    const float scale = fminf(fmaxf(orth_scale[0], 0.f), 1.f);
    const u16* Qc = QK + (size_t)2 * SPLANE + plane;   // z=1 Q plane, same (b,h)
#pragma unroll
    for (int s = 0; s < 4; s++) {
      const u16* qcrow = Qc + (size_t)(q0 + wave * 64 + s * 16 + fr) * 64;
      s16x8 qc0 = *(const s16x8*)&qcrow[fq * 8];
      s16x8 qc1 = *(const s16x8*)&qcrow[32 + fq * 8];
      float d = 0.f, nq = 0.f;
#pragma unroll
      for (int e = 0; e < 8; e++) {
        float a0 = bf2f((u16)qf[s][0][e]), a1 = bf2f((u16)qf[s][1][e]);
        float c0 = bf2f((u16)qc0[e]),      c1 = bf2f((u16)qc1[e]);
        d  = fmaf(a0, c0, fmaf(a1, c1, d));
        nq = fmaf(c0, c0, fmaf(c1, c1, nq));
      }
      d += __shfl_xor(d, 16);  d += __shfl_xor(d, 32);
      nq += __shfl_xor(nq, 16); nq += __shfl_xor(nq, 32);
      nq += 1e-5f;
      float coeff = fminf(fmaxf(d / nq, -1.f), 1.f);
      float sc = scale * coeff;
#pragma unroll
      for (int e = 0; e < 8; e++) {
        qf[s][0][e] = (short)f2bf(bf2f((u16)qf[s][0][e]) - sc * bf2f((u16)qc0[e]));
        qf[s][1][e] = (short)f2bf(bf2f((u16)qf[s][1][e]) - sc * bf2f((u16)qc1[e]));
      }
      if (lane < 16)
        atomicAdd(&sal[b * 1024 + q0 + wave * 64 + s * 16 + fr], fabsf(d) / sqrtf(nq));
    }
  }

  f32x4 oacc[4][4];            // [s][jt: d-tile], value (m = fq*4+r, d = jt*16+fr)
  float lsum[4];
#pragma unroll
  for (int s = 0; s < 4; s++) {
    lsum[s] = 0.f;
#pragma unroll
    for (int j = 0; j < 4; j++) oacc[s][j] = (f32x4){0.f, 0.f, 0.f, 0.f};
  }

  const int srow = tid >> 3, sc8 = (tid & 7) * 8;

  // prefetch tile 0
  uint4 rk0 = *(const uint4*)&K[(size_t)srow * 64 + sc8];
  uint4 rk1 = *(const uint4*)&K[(size_t)(srow + 32) * 64 + sc8];
  uint4 rv0 = *(const uint4*)&Vt[(size_t)srow * 1024 + sc8];
  uint4 rv1 = *(const uint4*)&Vt[(size_t)(srow + 32) * 1024 + sc8];

  for (int kv0 = 0; kv0 < 1024; kv0 += 64) {
    __syncthreads();                       // all waves done with previous tile
    *(uint4*)&lK[srow * AST + sc8]         = rk0;
    *(uint4*)&lK[(srow + 32) * AST + sc8]  = rk1;
    *(uint4*)&lVT[srow * AST + sc8]        = rv0;
    *(uint4*)&lVT[(srow + 32) * AST + sc8] = rv1;
    __syncthreads();                       // tile published

    // issue next tile's loads (clamped; redundant on last iter) — overlap compute
    {
      int nxt = (kv0 + 64) & 1023;
      const u16* kb = K + (size_t)nxt * 64;
      rk0 = *(const uint4*)&kb[(size_t)srow * 64 + sc8];
      rk1 = *(const uint4*)&kb[(size_t)(srow + 32) * 64 + sc8];
      const u16* vb = Vt + nxt;
      rv0 = *(const uint4*)&vb[(size_t)srow * 1024 + sc8];
      rv1 = *(const uint4*)&vb[(size_t)(srow + 32) * 1024 + sc8];
    }

#pragma unroll
    for (int ph = 0; ph < 2; ++ph) {           // n-half: n in [ph*32, ph*32+32)
#pragma unroll
      for (int jh = 0; jh < 2; ++jh) {
        const int jt = ph * 2 + jh;
        s16x8 kf0 = *(const s16x8*)&lK[(jt * 16 + fr) * AST + fq * 8];
        s16x8 kf1 = *(const s16x8*)&lK[(jt * 16 + fr) * AST + 32 + fq * 8];
#pragma unroll
        for (int s = 0; s < 4; s++) {
          f32x4 t = (f32x4){0.f, 0.f, 0.f, 0.f};
          t = __builtin_amdgcn_mfma_f32_16x16x32_bf16(kf0, qf[s][0], t, 0, 0, 0);
          t = __builtin_amdgcn_mfma_f32_16x16x32_bf16(kf1, qf[s][1], t, 0, 0, 0);
          float p0 = EXP2F(fmaf(t[0], 0.18033688f, -28.8539008f));
          float p1 = EXP2F(fmaf(t[1], 0.18033688f, -28.8539008f));
          float p2 = EXP2F(fmaf(t[2], 0.18033688f, -28.8539008f));
          float p3 = EXP2F(fmaf(t[3], 0.18033688f, -28.8539008f));
          lsum[s] += (p0 + p1) + (p2 + p3);
          uint2 pk; pk.x = pk_trunc(p0, p1); pk.y = pk_trunc(p2, p3);
          *(uint2*)&lP[(s * 16 + fr) * PST + jh * 16 + fq * 4] = pk;   // rows m, cols n-half
        }
      }
      WAIT_LGKM0;                     // wave-local LDS RAW on lP (vmcnt left in flight!)
      s16x8 pa[4];
#pragma unroll
      for (int s = 0; s < 4; s++) pa[s] = *(const s16x8*)&lP[(s * 16 + fr) * PST + fq * 8];
#pragma unroll
      for (int jt = 0; jt < 4; jt++) {
        s16x8 vb = *(const s16x8*)&lVT[(jt * 16 + fr) * AST + ph * 32 + fq * 8];
#pragma unroll
        for (int s = 0; s < 4; s++)
          oacc[s][jt] = __builtin_amdgcn_mfma_f32_16x16x32_bf16(pa[s], vb, oacc[s][jt], 0, 0, 0);
      }
    }
  }

  // lsum: reduce across the 4 fq-groups of each m-column, then distribute
#pragma unroll
  for (int s = 0; s < 4; s++) {
    float v = lsum[s];
    v += __shfl_xor(v, 16);
    v += __shfl_xor(v, 32);
    lsum[s] = v;                  // lanes 0..15 now hold totals for m = fr
  }
#pragma unroll
  for (int s = 0; s < 4; s++) {
#pragma unroll
    for (int r = 0; r < 4; r++) {
      float inv = 1.f / __shfl(lsum[s], fq * 4 + r);
      int t = q0 + wave * 64 + s * 16 + fq * 4 + r;
      size_t base = ((size_t)z * 8192 + b * 1024 + t) * 768 + hd * 64 + fr;
#pragma unroll
      for (int jt = 0; jt < 4; jt++)
        aout[base + jt * 16] = f2bf(oacc[s][jt][r] * inv);
    }
  }
}

// ---------------- proj GEMM + bias -> bf16 (BK=64, swizzled, C^T, LDS epilogue) ---------
// XCD-grouped swizzle: grid 768 = 8 XCD x 96. First 32 blocks also finalize saliency
// (sal = clip(sal/12)) — attn completed before proj launches (stream order).
__global__ __launch_bounds__(256) void k_proj_gemm(const u16* __restrict__ A,
                                                   const u16* __restrict__ Wp,
                                                   const float* __restrict__ bias_id,
                                                   const float* __restrict__ bias_cl,
                                                   float* __restrict__ sal,
                                                   u16* __restrict__ out) {
  __shared__ __align__(16) u16 sm[18432];   // lA 8192 | lB 8192 / epilogue union
  u16* lA = sm;
  u16* lB = sm + 8192;
  const int idx = blockIdx.x;               // 0..767
  const int tid = threadIdx.x;
  if (idx < 32) {
    int i2 = idx * 256 + tid;               // 8192 saliency rows
    float v = sal[i2] * (1.f / 12.f);
    sal[i2] = fminf(fmaxf(v, 0.f), 1.f);
  }
  const int swz = (idx & 7) * 96 + (idx >> 3);
  const int bx = swz % 6;
  const int rem = swz / 6;                  // 0..127
  const int by = rem & 63;
  const int z = rem >> 6;
  const int n0 = bx * 128, m0 = by * 128;
  const u16* Az = A + (size_t)z * 8192 * 768;
  const u16* Wz = Wp + (size_t)z * 768 * 768;
  const float* bias = z ? bias_cl : bias_id;
  u16* oz = out + (size_t)z * 8192 * 768;
  const int wave = tid >> 6, lane = tid & 63;
  const int wr = (wave >> 1) * 64, wc = (wave & 1) * 64;
  const int fr = lane & 15, fq = lane >> 4;

  float bv[4][4];
#pragma unroll
  for (int i = 0; i < 4; i++)
#pragma unroll
    for (int r = 0; r < 4; r++) bv[i][r] = bias[n0 + wc + i * 16 + fq * 4 + r];

  f32x4 acc[4][4];
#pragma unroll
  for (int i = 0; i < 4; i++)
#pragma unroll
    for (int j = 0; j < 4; j++) acc[i][j] = (f32x4){0.f, 0.f, 0.f, 0.f};

  const int srow = lane >> 3;
  const int scol = ((lane & 7) ^ srow) * 8;

  // per-thread staging base pointers (row + swizzled chunk folded in)
  const u16* pAz = Az + (size_t)(m0 + wave * 32 + srow) * 768 + scol;
  const u16* pWz = Wz + (size_t)(n0 + wave * 32 + srow) * 768 + scol;

  for (int k0 = 0; k0 < 768; k0 += 64) {
    __syncthreads();
#pragma unroll
    for (int it = 0; it < 4; ++it) {
      int rb = wave * 32 + it * 8;
      g2l16(pAz + it * (8 * 768) + k0, &lA[rb * 64]);
      g2l16(pWz + it * (8 * 768) + k0, &lB[rb * 64]);
    }
    __syncthreads();
#pragma unroll
    for (int ks = 0; ks < 2; ++ks) {
      s16x8 af[4], bfr[4];
#pragma unroll
      for (int i = 0; i < 4; i++) {
        int row = wc + i * 16 + fr;
        af[i] = *(const s16x8*)&lB[row * 64 + (((ks * 4 + fq) ^ (row & 7)) * 8)];
      }
#pragma unroll
      for (int j = 0; j < 4; j++) {
        int row = wr + j * 16 + fr;
        bfr[j] = *(const s16x8*)&lA[row * 64 + (((ks * 4 + fq) ^ (row & 7)) * 8)];
      }
#pragma unroll
      for (int i = 0; i < 4; i++)
#pragma unroll
        for (int j = 0; j < 4; j++)
          acc[i][j] = __builtin_amdgcn_mfma_f32_16x16x32_bf16(af[i], bfr[j], acc[i][j], 0, 0, 0);
    }
  }

  __syncthreads();
  u16* ep = sm + wave * 4608;      // 64 t-rows x 72 stride (c cols)
#pragma unroll
  for (int i = 0; i < 4; i++)
#pragma unroll
    for (int j = 0; j < 4; j++) {
      unsigned int lo = (unsigned int)f2bf(acc[i][j][0] + bv[i][0]) |
                        ((unsigned int)f2bf(acc[i][j][1] + bv[i][1]) << 16);
      unsigned int hi = (unsigned int)f2bf(acc[i][j][2] + bv[i][2]) |
                        ((unsigned int)f2bf(acc[i][j][3] + bv[i][3]) << 16);
      uint2 pk; pk.x = lo; pk.y = hi;
      *(uint2*)&ep[(j * 16 + fr) * 72 + i * 16 + fq * 4] = pk;
    }
  __builtin_amdgcn_s_waitcnt(0);

  const int c0 = n0 + wc;
#pragma unroll
  for (int pass = 0; pass < 8; ++pass) {
    int row = pass * 8 + (lane >> 3);
    int dch = (lane & 7) * 8;
    u16* dst = oz + (size_t)(m0 + wr + row) * 768 + c0;
    *(uint4*)&dst[dch] = *(const uint4*)&ep[row * 72 + dch];
  }
}

// ---------------- LayerNorm (bf16 in, fp32 out) ----------------
__global__ __launch_bounds__(256) void k_ln(const u16* __restrict__ pin,
                                            const float* __restrict__ w_id,
                                            const float* __restrict__ b_id,
                                            const float* __restrict__ w_cl,
                                            const float* __restrict__ b_cl,
                                            float* __restrict__ out) {
  __shared__ float red[2][8];
  const int row = blockIdx.x;     // 0..16383
  const int z = row >> 13;
  const float* w = z ? w_cl : w_id;
  const float* bb = z ? b_cl : b_id;
  const u16* x = pin + (size_t)row * 768;
  float v[3];
  float s = 0.f, s2 = 0.f;
#pragma unroll
  for (int i = 0; i < 3; i++) {
    v[i] = bf2f(x[threadIdx.x + i * 256]);
    s += v[i];
    s2 += v[i] * v[i];
  }
#pragma unroll
  for (int sh = 1; sh < 64; sh <<= 1) { s += __shfl_xor(s, sh); s2 += __shfl_xor(s2, sh); }
  const int wave = threadIdx.x >> 6, lane = threadIdx.x & 63;
  if (lane == 0) { red[0][wave] = s; red[1][wave] = s2; }
  __syncthreads();
  s = red[0][0] + red[0][1] + red[0][2] + red[0][3];
  s2 = red[1][0] + red[1][1] + red[1][2] + red[1][3];
  float mu = s * (1.f / 768.f);
  float var = s2 * (1.f / 768.f) - mu * mu;
  float rstd = rsqrtf(fmaxf(var, 0.f) + 1e-5f);
  float* o = out + (size_t)row * 768;
#pragma unroll
  for (int i = 0; i < 3; i++) {
    int c = threadIdx.x + i * 256;
    o[c] = (v[i] - mu) * rstd * w[c] + bb[c];
  }
}

extern "C" void kernel_launch(void* const* d_in, const int* in_sizes, int n_in,
                              void* d_out, int out_size, void* d_ws, size_t ws_size,
                              hipStream_t stream) {
  const float* x        = (const float*)d_in[0];
  const float* w_qkv_id = (const float*)d_in[1];
  const float* w_qkv_cl = (const float*)d_in[2];
  const float* w_proj_id= (const float*)d_in[3];
  const float* b_proj_id= (const float*)d_in[4];
  const float* w_proj_cl= (const float*)d_in[5];
  const float* b_proj_cl= (const float*)d_in[6];
  const float* ln_id_w  = (const float*)d_in[7];
  const float* ln_id_b  = (const float*)d_in[8];
  const float* ln_cl_w  = (const float*)d_in[9];
  const float* ln_cl_b  = (const float*)d_in[10];
  const float* orth     = (const float*)d_in[11];
  float* out = (float*)d_out;
  float* sal = out + 12582912;

  // workspace layout (122.68 MB total)
  u16* xb    = (u16*)d_ws;                   //  6,291,456 u16
  u16* wqkv  = xb + 6291456;                 //  3,538,944 u16 (id then cloth)
  u16* wproj = wqkv + 3538944;               //  1,179,648 u16 (id then cloth)
  u16* qk    = wproj + 1179648;              // 25,165,824 u16 [2][{q,k}][b][h][n][d]
  u16* vt    = qk + 25165824;                // 12,582,912 u16 [2][b][h][d][n]
  u16* aout  = vt + 12582912;                // 12,582,912 u16 [2][B*N][C]
  u16* pout  = qk;                           // bf16 proj out aliases dead qk

  k_cvt<<<10752, 256, 0, stream>>>(x, w_qkv_id, w_qkv_cl, w_proj_id, w_proj_cl,
                                   xb, wqkv, wproj);
  k_qkv_gemm<<<2304, 256, 0, stream>>>(xb, wqkv, qk, vt, sal);
  k_attn<<<768, 256, 0, stream>>>(qk, vt, orth, sal, aout);
  k_proj_gemm<<<768, 256, 0, stream>>>(aout, wproj, b_proj_id, b_proj_cl, sal, pout);
  k_ln<<<16384, 256, 0, stream>>>(pout, ln_id_w, ln_id_b, ln_cl_w, ln_cl_b, out);
}